// Round 1
// baseline (543.286 us; speedup 1.0000x reference)
//
#include <hip/hip_runtime.h>
#include <hip/hip_bf16.h>

typedef __attribute__((ext_vector_type(8))) short bf16x8;
typedef __attribute__((ext_vector_type(4))) float f32x4;

#define BM 128
#define BN 128
#define BK 64

__device__ __forceinline__ unsigned short f2b(float f) {
    union { float f; unsigned int u; } x; x.f = f;
    unsigned int r = x.u + 0x7fffu + ((x.u >> 16) & 1u);
    return (unsigned short)(r >> 16);
}

__device__ __forceinline__ float sigmoidf_(float v) {
    return 1.0f / (1.0f + __expf(-v));
}
__device__ __forceinline__ float tanhf_(float v) {
    return 1.0f - 2.0f / (__expf(2.0f * v) + 1.0f);
}

__device__ __forceinline__ void gll16(const void* g, void* l) {
    __builtin_amdgcn_global_load_lds(
        (const __attribute__((address_space(1))) void*)g,
        (__attribute__((address_space(3))) void*)l,
        16, 0, 0);
}

// Core: C[128x128] tile of A(M x lda) * B(N x ldb)^T, both bf16 K-contiguous.
// 4 waves, each 64x64 via 4x4 grid of 16x16x32 MFMAs.
__device__ __forceinline__ void mma_core(
    const unsigned short* __restrict__ A, int lda,
    const unsigned short* __restrict__ B, int ldb,
    int m0, int n0, int nk, int remap_from, int remap_add,
    unsigned short* As, unsigned short* Bs, f32x4 acc[4][4])
{
    const int t = threadIdx.x;
    const int lane = t & 63;
    const int wm = (t >> 7) & 1;
    const int wn = (t >> 6) & 1;
    const int srow = t >> 3;         // staging row within group of 32
    const int scol = (t & 7) * 8;    // staging col (8 bf16 = 16B)

    for (int kt = 0; kt < nk; ++kt) {
        int k0 = kt * BK + (kt >= remap_from ? remap_add : 0);
        __syncthreads();
        #pragma unroll
        for (int j = 0; j < 4; ++j) {
            int row = j * 32 + srow;
            gll16(A + (size_t)(m0 + row) * lda + k0 + scol, As + row * BK + scol);
            gll16(B + (size_t)(n0 + row) * ldb + k0 + scol, Bs + row * BK + scol);
        }
        __syncthreads();
        #pragma unroll
        for (int kk = 0; kk < 2; ++kk) {
            bf16x8 af[4], bfr[4];
            const int ko = kk * 32 + (lane >> 4) * 8;
            const int ra = (wm * 64 + (lane & 15)) * BK + ko;
            const int rb = (wn * 64 + (lane & 15)) * BK + ko;
            #pragma unroll
            for (int i = 0; i < 4; ++i)
                af[i] = *(const bf16x8*)(As + ra + i * 16 * BK);
            #pragma unroll
            for (int j = 0; j < 4; ++j)
                bfr[j] = *(const bf16x8*)(Bs + rb + j * 16 * BK);
            #pragma unroll
            for (int i = 0; i < 4; ++i)
                #pragma unroll
                for (int j = 0; j < 4; ++j)
                    acc[i][j] = __builtin_amdgcn_mfma_f32_16x16x32_bf16(
                        af[i], bfr[j], acc[i][j], 0, 0, 0);
        }
    }
}

// GEMM1: S = Xall(8192x4096) @ Wcat(3072x4096)^T, fused gate epilogues.
// grid = (24, 64): blockIdx.x = n-block (gate = bn>>3), blockIdx.y = m-block.
__global__ __launch_bounds__(256) void gemm1(
    const unsigned short* __restrict__ Xall,
    const unsigned short* __restrict__ Wcat,
    const float* __restrict__ hprev,
    const float* __restrict__ br, const float* __restrict__ bz,
    unsigned short* __restrict__ rh,   // bf16 8192x1024
    float* __restrict__ zout,          // fp32 8192x1024 (aliases d_out)
    float* __restrict__ shp)           // fp32 8192x1024
{
    __shared__ __attribute__((aligned(16))) unsigned short As[BM * BK];
    __shared__ __attribute__((aligned(16))) unsigned short Bs[BN * BK];
    f32x4 acc[4][4] = {};

    const int bn = blockIdx.x, bm = blockIdx.y;
    const int gate = bn >> 3;          // 0=r, 1=z, 2=h
    const int m0 = bm * BM, n0 = bn * BN;
    const int nk = (gate == 2) ? 48 : 64;                 // gate h skips dead Uh segment
    const int rfrom = (gate == 2) ? 16 : (1 << 30);

    mma_core(Xall, 4096, Wcat, 4096, m0, n0, nk, rfrom, 1024, As, Bs, acc);

    const int lane = threadIdx.x & 63;
    const int wm = (threadIdx.x >> 7) & 1, wn = (threadIdx.x >> 6) & 1;
    const int rowb = m0 + wm * 64 + (lane >> 4) * 4;
    const int colb = (n0 - gate * 1024) + wn * 64 + (lane & 15);

    if (gate == 0) {
        #pragma unroll
        for (int i = 0; i < 4; ++i)
            #pragma unroll
            for (int r = 0; r < 4; ++r) {
                int m = rowb + i * 16 + r;
                #pragma unroll
                for (int j = 0; j < 4; ++j) {
                    int n = colb + j * 16;
                    size_t idx = (size_t)m * 1024 + n;
                    float rr = sigmoidf_(acc[i][j][r] + br[n]);
                    rh[idx] = f2b(rr * hprev[idx]);
                }
            }
    } else if (gate == 1) {
        #pragma unroll
        for (int i = 0; i < 4; ++i)
            #pragma unroll
            for (int r = 0; r < 4; ++r) {
                int m = rowb + i * 16 + r;
                #pragma unroll
                for (int j = 0; j < 4; ++j) {
                    int n = colb + j * 16;
                    size_t idx = (size_t)m * 1024 + n;
                    zout[idx] = sigmoidf_(acc[i][j][r] + bz[n]);
                }
            }
    } else {
        #pragma unroll
        for (int i = 0; i < 4; ++i)
            #pragma unroll
            for (int r = 0; r < 4; ++r) {
                int m = rowb + i * 16 + r;
                #pragma unroll
                for (int j = 0; j < 4; ++j) {
                    int n = colb + j * 16;
                    size_t idx = (size_t)m * 1024 + n;
                    shp[idx] = acc[i][j][r];
                }
            }
    }
}

// GEMM2: Sh2 = rh(8192x1024) @ Uhb(1024x1024)^T; epilogue computes final output.
// grid = (8, 64).
__global__ __launch_bounds__(256) void gemm2(
    const unsigned short* __restrict__ rh,
    const unsigned short* __restrict__ Uhb,
    const float* __restrict__ shp, const float* __restrict__ bh,
    const float* __restrict__ hprev,
    float* __restrict__ zo)            // in: z, out: final (d_out)
{
    __shared__ __attribute__((aligned(16))) unsigned short As[BM * BK];
    __shared__ __attribute__((aligned(16))) unsigned short Bs[BN * BK];
    f32x4 acc[4][4] = {};

    const int bn = blockIdx.x, bm = blockIdx.y;
    const int m0 = bm * BM, n0 = bn * BN;

    mma_core(rh, 1024, Uhb, 1024, m0, n0, 16, 1 << 30, 0, As, Bs, acc);

    const int lane = threadIdx.x & 63;
    const int wm = (threadIdx.x >> 7) & 1, wn = (threadIdx.x >> 6) & 1;
    const int rowb = m0 + wm * 64 + (lane >> 4) * 4;
    const int colb = n0 + wn * 64 + (lane & 15);

    #pragma unroll
    for (int i = 0; i < 4; ++i)
        #pragma unroll
        for (int r = 0; r < 4; ++r) {
            int m = rowb + i * 16 + r;
            #pragma unroll
            for (int j = 0; j < 4; ++j) {
                int n = colb + j * 16;
                size_t idx = (size_t)m * 1024 + n;
                float val = acc[i][j][r] + shp[idx] + bh[n];
                float hp = tanhf_(val);
                float zv = zo[idx];
                zo[idx] = zv * hp + (1.0f - zv) * hprev[idx];
            }
        }
}

// fp32 -> bf16 strided copy-cast, 12 jobs in one launch. grid = (4096, 12).
struct CastJobs {
    const float* src[12];
    unsigned short* dst[12];   // pre-offset by dst col0
    int n4[12];                // float4 count
    int colshift[12];          // log2(src cols)
    int stride[12];            // dst row stride in elements
};

__global__ __launch_bounds__(256) void cast_all(CastJobs jb) {
    const int job = blockIdx.y;
    const float4* src = (const float4*)jb.src[job];
    unsigned short* dst = jb.dst[job];
    const int n4 = jb.n4[job];
    const int cs2 = jb.colshift[job] - 2;   // shift in vec4 units
    const int stride = jb.stride[job];
    const int cmask = (1 << cs2) - 1;
    for (int i = blockIdx.x * blockDim.x + threadIdx.x; i < n4;
         i += gridDim.x * blockDim.x) {
        float4 v = src[i];
        int row = i >> cs2;
        int col = (i & cmask) * 4;
        ushort4 o;
        o.x = f2b(v.x); o.y = f2b(v.y); o.z = f2b(v.z); o.w = f2b(v.w);
        *(ushort4*)(dst + (size_t)row * stride + col) = o;
    }
}

extern "C" void kernel_launch(void* const* d_in, const int* in_sizes, int n_in,
                              void* d_out, int out_size, void* d_ws, size_t ws_size,
                              hipStream_t stream) {
    const float* x     = (const float*)d_in[0];
    const float* hprev = (const float*)d_in[1];
    const float* c     = (const float*)d_in[2];
    const float* Wh    = (const float*)d_in[3];
    const float* Wz    = (const float*)d_in[4];
    const float* Wr    = (const float*)d_in[5];
    const float* Uh    = (const float*)d_in[6];
    const float* Uz    = (const float*)d_in[7];
    const float* Ur    = (const float*)d_in[8];
    const float* Ch    = (const float*)d_in[9];
    const float* Cz    = (const float*)d_in[10];
    const float* Cr    = (const float*)d_in[11];
    const float* bh    = (const float*)d_in[12];
    const float* bz    = (const float*)d_in[13];
    const float* br    = (const float*)d_in[14];

    char* ws = (char*)d_ws;
    unsigned short* Xall = (unsigned short*)ws; ws += (size_t)8192 * 4096 * 2;
    unsigned short* Wcat = (unsigned short*)ws; ws += (size_t)3072 * 4096 * 2;
    unsigned short* Uhb  = (unsigned short*)ws; ws += (size_t)1024 * 1024 * 2;
    unsigned short* rhb  = (unsigned short*)ws; ws += (size_t)8192 * 1024 * 2;
    float* shp           = (float*)ws;          ws += (size_t)8192 * 1024 * 4;
    float* zo = (float*)d_out;   // z staged in d_out, overwritten with final out

    CastJobs jb;
    auto setjob = [&](int j, const float* s, unsigned short* dbase, int col0,
                      int rows, int cols, int stride) {
        jb.src[j] = s; jb.dst[j] = dbase + col0;
        jb.n4[j] = rows * cols / 4;
        jb.colshift[j] = (cols == 2048) ? 11 : 10;
        jb.stride[j] = stride;
    };
    // Xall = [x | hprev | c]
    setjob(0, x,     Xall, 0,    8192, 1024, 4096);
    setjob(1, hprev, Xall, 1024, 8192, 1024, 4096);
    setjob(2, c,     Xall, 2048, 8192, 2048, 4096);
    // Wcat rows 0..1023 = [Wr|Ur|Cr]
    setjob(3, Wr, Wcat, 0,    1024, 1024, 4096);
    setjob(4, Ur, Wcat, 1024, 1024, 1024, 4096);
    setjob(5, Cr, Wcat, 2048, 1024, 2048, 4096);
    // rows 1024..2047 = [Wz|Uz|Cz]
    setjob(6, Wz, Wcat + 1024 * 4096, 0,    1024, 1024, 4096);
    setjob(7, Uz, Wcat + 1024 * 4096, 1024, 1024, 1024, 4096);
    setjob(8, Cz, Wcat + 1024 * 4096, 2048, 1024, 2048, 4096);
    // rows 2048..3071 = [Wh|unused|Ch] (dead segment never read: gate-h K-loop skips it)
    setjob(9,  Wh, Wcat + 2048 * 4096, 0,    1024, 1024, 4096);
    setjob(10, Ch, Wcat + 2048 * 4096, 2048, 1024, 2048, 4096);
    // Uh standalone
    setjob(11, Uh, Uhb, 0, 1024, 1024, 1024);

    hipLaunchKernelGGL(cast_all, dim3(4096, 12), dim3(256), 0, stream, jb);
    hipLaunchKernelGGL(gemm1, dim3(24, 64), dim3(256), 0, stream,
                       Xall, Wcat, hprev, br, bz, rhb, zo, shp);
    hipLaunchKernelGGL(gemm2, dim3(8, 64), dim3(256), 0, stream,
                       rhb, Uhb, shp, bh, hprev, zo);
}

// Round 2
// 497.721 us; speedup vs baseline: 1.0915x; 1.0915x over previous
//
#include <hip/hip_runtime.h>
#include <hip/hip_bf16.h>

typedef __attribute__((ext_vector_type(8))) short bf16x8;
typedef __attribute__((ext_vector_type(8))) unsigned short u16x8;
typedef __attribute__((ext_vector_type(4))) float f32x4;

#define BM 128
#define BN 128
#define BK 64

__device__ __forceinline__ unsigned short f2b(float f) {
    union { float f; unsigned int u; } x; x.f = f;
    unsigned int r = x.u + 0x7fffu + ((x.u >> 16) & 1u);
    return (unsigned short)(r >> 16);
}

__device__ __forceinline__ float sigmoidf_(float v) {
    return 1.0f / (1.0f + __expf(-v));
}
__device__ __forceinline__ float tanhf_(float v) {
    return 1.0f - 2.0f / (__expf(2.0f * v) + 1.0f);
}

__device__ __forceinline__ void gll16(const void* g, void* l) {
    __builtin_amdgcn_global_load_lds(
        (const __attribute__((address_space(1))) void*)g,
        (__attribute__((address_space(3))) void*)l,
        16, 0, 0);
}

// Core: C[128x128] tile of A(M x lda) * B(N x ldb)^T, both bf16 K-contiguous.
// 4 waves, each 64x64 via 4x4 grid of 16x16x32 MFMAs.
// LDS layout is XOR-swizzled: physical 16B-block p in row r holds global
// column-block p ^ (r&7). Staging keeps LDS dest = base + lane*16 (required
// by global_load_lds) and swizzles the GLOBAL source column instead.
__device__ __forceinline__ void mma_core(
    const unsigned short* __restrict__ A, int lda,
    const unsigned short* __restrict__ B, int ldb,
    int m0, int n0, int nk, int remap_from, int remap_add,
    unsigned short* As, unsigned short* Bs, f32x4 acc[4][4])
{
    const int t = threadIdx.x;
    const int lane = t & 63;
    const int wm = (t >> 7) & 1;
    const int wn = (t >> 6) & 1;
    const int srow = t >> 3;                         // staging row (0..31)
    const int ldsCol = (t & 7) * 8;                  // physical LDS col (elems)
    const int swc = (((t & 7) ^ ((t >> 3) & 7))) * 8;  // swizzled global col

    for (int kt = 0; kt < nk; ++kt) {
        int k0 = kt * BK + (kt >= remap_from ? remap_add : 0);
        __syncthreads();
        #pragma unroll
        for (int j = 0; j < 4; ++j) {
            int row = j * 32 + srow;
            gll16(A + (size_t)(m0 + row) * lda + k0 + swc, As + row * BK + ldsCol);
            gll16(B + (size_t)(n0 + row) * ldb + k0 + swc, Bs + row * BK + ldsCol);
        }
        __syncthreads();
        #pragma unroll
        for (int kk = 0; kk < 2; ++kk) {
            bf16x8 af[4], bfr[4];
            // fragment row r satisfies r&7 == lane&7, so swizzle is (lane&7)
            const int off = (((kk * 4 + (lane >> 4)) ^ (lane & 7))) * 8;
            const int ra = (wm * 64 + (lane & 15)) * BK + off;
            const int rb = (wn * 64 + (lane & 15)) * BK + off;
            #pragma unroll
            for (int i = 0; i < 4; ++i)
                af[i] = *(const bf16x8*)(As + ra + i * 16 * BK);
            #pragma unroll
            for (int j = 0; j < 4; ++j)
                bfr[j] = *(const bf16x8*)(Bs + rb + j * 16 * BK);
            #pragma unroll
            for (int i = 0; i < 4; ++i)
                #pragma unroll
                for (int j = 0; j < 4; ++j)
                    acc[i][j] = __builtin_amdgcn_mfma_f32_16x16x32_bf16(
                        af[i], bfr[j], acc[i][j], 0, 0, 0);
        }
    }
}

// GEMM1: S = Xall(8192x4096) @ Wcat(3072x4096)^T, fused gate epilogues.
// grid = 1536 linear blocks; XCD-swizzled to 16bm x 12bn regions per XCD.
__global__ __launch_bounds__(256) void gemm1(
    const unsigned short* __restrict__ Xall,
    const unsigned short* __restrict__ Wcat,
    const float* __restrict__ hprev,
    const float* __restrict__ br, const float* __restrict__ bz,
    unsigned short* __restrict__ rh,   // bf16 8192x1024
    float* __restrict__ zout,          // fp32 8192x1024 (aliases d_out)
    float* __restrict__ shp)           // fp32 8192x1024
{
    __shared__ __attribute__((aligned(16))) unsigned short As[BM * BK];
    __shared__ __attribute__((aligned(16))) unsigned short Bs[BN * BK];
    f32x4 acc[4][4] = {};

    // XCD swizzle: consecutive flat ids round-robin XCDs; give each XCD a
    // contiguous 16bm x 12bn region so its L2 holds 16MB A + 12MB B once.
    const int flat = blockIdx.y * gridDim.x + blockIdx.x;
    const int xcd = flat & 7;
    const int p = flat >> 3;                 // 0..191
    const int bm = (xcd >> 1) * 16 + (p & 15);
    const int bn = (xcd & 1) * 12 + (p >> 4);

    const int gate = (bn * BN) >> 10;        // 0=r, 1=z, 2=h
    const int m0 = bm * BM, n0 = bn * BN;
    const int nk = (gate == 2) ? 48 : 64;    // gate h skips dead Uh segment
    const int rfrom = (gate == 2) ? 16 : (1 << 30);

    mma_core(Xall, 4096, Wcat, 4096, m0, n0, nk, rfrom, 1024, As, Bs, acc);

    const int lane = threadIdx.x & 63;
    const int wm = (threadIdx.x >> 7) & 1, wn = (threadIdx.x >> 6) & 1;
    const int rowb = m0 + wm * 64 + (lane >> 4) * 4;
    const int colb = (n0 - gate * 1024) + wn * 64 + (lane & 15);

    if (gate == 0) {
        #pragma unroll
        for (int i = 0; i < 4; ++i)
            #pragma unroll
            for (int r = 0; r < 4; ++r) {
                int m = rowb + i * 16 + r;
                #pragma unroll
                for (int j = 0; j < 4; ++j) {
                    int n = colb + j * 16;
                    size_t idx = (size_t)m * 1024 + n;
                    float rr = sigmoidf_(acc[i][j][r] + br[n]);
                    rh[idx] = f2b(rr * hprev[idx]);
                }
            }
    } else if (gate == 1) {
        #pragma unroll
        for (int i = 0; i < 4; ++i)
            #pragma unroll
            for (int r = 0; r < 4; ++r) {
                int m = rowb + i * 16 + r;
                #pragma unroll
                for (int j = 0; j < 4; ++j) {
                    int n = colb + j * 16;
                    size_t idx = (size_t)m * 1024 + n;
                    zout[idx] = sigmoidf_(acc[i][j][r] + bz[n]);
                }
            }
    } else {
        #pragma unroll
        for (int i = 0; i < 4; ++i)
            #pragma unroll
            for (int r = 0; r < 4; ++r) {
                int m = rowb + i * 16 + r;
                #pragma unroll
                for (int j = 0; j < 4; ++j) {
                    int n = colb + j * 16;
                    size_t idx = (size_t)m * 1024 + n;
                    shp[idx] = acc[i][j][r];
                }
            }
    }
}

// GEMM2: Sh2 = rh(8192x1024) @ Uhb(1024x1024)^T; epilogue computes final out.
// grid = 512 linear blocks; 8bm x 8bn region per XCD.
__global__ __launch_bounds__(256) void gemm2(
    const unsigned short* __restrict__ rh,
    const unsigned short* __restrict__ Uhb,
    const float* __restrict__ shp, const float* __restrict__ bh,
    const float* __restrict__ hprev,
    float* __restrict__ zo)            // in: z, out: final (d_out)
{
    __shared__ __attribute__((aligned(16))) unsigned short As[BM * BK];
    __shared__ __attribute__((aligned(16))) unsigned short Bs[BN * BK];
    f32x4 acc[4][4] = {};

    const int flat = blockIdx.y * gridDim.x + blockIdx.x;
    const int xcd = flat & 7;
    const int p = flat >> 3;                 // 0..63
    const int bm = xcd * 8 + (p & 7);
    const int bn = p >> 3;
    const int m0 = bm * BM, n0 = bn * BN;

    mma_core(rh, 1024, Uhb, 1024, m0, n0, 16, 1 << 30, 0, As, Bs, acc);

    const int lane = threadIdx.x & 63;
    const int wm = (threadIdx.x >> 7) & 1, wn = (threadIdx.x >> 6) & 1;
    const int rowb = m0 + wm * 64 + (lane >> 4) * 4;
    const int colb = n0 + wn * 64 + (lane & 15);

    #pragma unroll
    for (int i = 0; i < 4; ++i)
        #pragma unroll
        for (int r = 0; r < 4; ++r) {
            int m = rowb + i * 16 + r;
            #pragma unroll
            for (int j = 0; j < 4; ++j) {
                int n = colb + j * 16;
                size_t idx = (size_t)m * 1024 + n;
                float val = acc[i][j][r] + shp[idx] + bh[n];
                float hp = tanhf_(val);
                float zv = zo[idx];
                zo[idx] = zv * hp + (1.0f - zv) * hprev[idx];
            }
        }
}

// fp32 -> bf16 strided copy-cast, 12 jobs in one launch. 8 floats/thread,
// 16B stores. grid = (2048, 12).
struct CastJobs {
    const float* src[12];
    unsigned short* dst[12];   // pre-offset by dst col0
    int n8[12];                // groups of 8 floats
    int cs3[12];               // log2(src cols) - 3
    int stride[12];            // dst row stride in elements
};

__global__ __launch_bounds__(256) void cast_all(CastJobs jb) {
    const int job = blockIdx.y;
    const float4* src = (const float4*)jb.src[job];
    unsigned short* dst = jb.dst[job];
    const int n8 = jb.n8[job];
    const int cs3 = jb.cs3[job];
    const int stride = jb.stride[job];
    const int cmask = (1 << cs3) - 1;
    for (int i = blockIdx.x * blockDim.x + threadIdx.x; i < n8;
         i += gridDim.x * blockDim.x) {
        float4 a = src[2 * i];
        float4 b = src[2 * i + 1];
        int row = i >> cs3;
        int col = (i & cmask) * 8;
        u16x8 o;
        o[0] = f2b(a.x); o[1] = f2b(a.y); o[2] = f2b(a.z); o[3] = f2b(a.w);
        o[4] = f2b(b.x); o[5] = f2b(b.y); o[6] = f2b(b.z); o[7] = f2b(b.w);
        *(u16x8*)(dst + (size_t)row * stride + col) = o;
    }
}

extern "C" void kernel_launch(void* const* d_in, const int* in_sizes, int n_in,
                              void* d_out, int out_size, void* d_ws, size_t ws_size,
                              hipStream_t stream) {
    const float* x     = (const float*)d_in[0];
    const float* hprev = (const float*)d_in[1];
    const float* c     = (const float*)d_in[2];
    const float* Wh    = (const float*)d_in[3];
    const float* Wz    = (const float*)d_in[4];
    const float* Wr    = (const float*)d_in[5];
    const float* Uh    = (const float*)d_in[6];
    const float* Uz    = (const float*)d_in[7];
    const float* Ur    = (const float*)d_in[8];
    const float* Ch    = (const float*)d_in[9];
    const float* Cz    = (const float*)d_in[10];
    const float* Cr    = (const float*)d_in[11];
    const float* bh    = (const float*)d_in[12];
    const float* bz    = (const float*)d_in[13];
    const float* br    = (const float*)d_in[14];

    char* ws = (char*)d_ws;
    unsigned short* Xall = (unsigned short*)ws; ws += (size_t)8192 * 4096 * 2;
    unsigned short* Wcat = (unsigned short*)ws; ws += (size_t)3072 * 4096 * 2;
    unsigned short* Uhb  = (unsigned short*)ws; ws += (size_t)1024 * 1024 * 2;
    unsigned short* rhb  = (unsigned short*)ws; ws += (size_t)8192 * 1024 * 2;
    float* shp           = (float*)ws;          ws += (size_t)8192 * 1024 * 4;
    float* zo = (float*)d_out;   // z staged in d_out, overwritten with final out

    CastJobs jb;
    auto setjob = [&](int j, const float* s, unsigned short* dbase, int col0,
                      int rows, int cols, int stride) {
        jb.src[j] = s; jb.dst[j] = dbase + col0;
        jb.n8[j] = rows * cols / 8;
        jb.cs3[j] = (cols == 2048) ? 8 : 7;
        jb.stride[j] = stride;
    };
    // Xall = [x | hprev | c]
    setjob(0, x,     Xall, 0,    8192, 1024, 4096);
    setjob(1, hprev, Xall, 1024, 8192, 1024, 4096);
    setjob(2, c,     Xall, 2048, 8192, 2048, 4096);
    // Wcat rows 0..1023 = [Wr|Ur|Cr]
    setjob(3, Wr, Wcat, 0,    1024, 1024, 4096);
    setjob(4, Ur, Wcat, 1024, 1024, 1024, 4096);
    setjob(5, Cr, Wcat, 2048, 1024, 2048, 4096);
    // rows 1024..2047 = [Wz|Uz|Cz]
    setjob(6, Wz, Wcat + 1024 * 4096, 0,    1024, 1024, 4096);
    setjob(7, Uz, Wcat + 1024 * 4096, 1024, 1024, 1024, 4096);
    setjob(8, Cz, Wcat + 1024 * 4096, 2048, 1024, 2048, 4096);
    // rows 2048..3071 = [Wh|unused|Ch] (dead segment never read: gate-h K-loop skips it)
    setjob(9,  Wh, Wcat + 2048 * 4096, 0,    1024, 1024, 4096);
    setjob(10, Ch, Wcat + 2048 * 4096, 2048, 1024, 2048, 4096);
    // Uh standalone
    setjob(11, Uh, Uhb, 0, 1024, 1024, 1024);

    hipLaunchKernelGGL(cast_all, dim3(2048, 12), dim3(256), 0, stream, jb);
    hipLaunchKernelGGL(gemm1, dim3(24, 64), dim3(256), 0, stream,
                       Xall, Wcat, hprev, br, bz, rhb, zo, shp);
    hipLaunchKernelGGL(gemm2, dim3(8, 64), dim3(256), 0, stream,
                       rhb, Uhb, shp, bh, hprev, zo);
}

// Round 3
// 438.878 us; speedup vs baseline: 1.2379x; 1.1341x over previous
//
#include <hip/hip_runtime.h>
#include <hip/hip_bf16.h>

typedef __attribute__((ext_vector_type(8))) short bf16x8;
typedef __attribute__((ext_vector_type(8))) unsigned short u16x8;
typedef __attribute__((ext_vector_type(4))) float f32x4;

#define BM 128
#define BN 128
#define BK 64

__device__ __forceinline__ unsigned short f2b(float f) {
    union { float f; unsigned int u; } x; x.f = f;
    unsigned int r = x.u + 0x7fffu + ((x.u >> 16) & 1u);
    return (unsigned short)(r >> 16);
}

__device__ __forceinline__ float sigmoidf_(float v) {
    return 1.0f / (1.0f + __expf(-v));
}
__device__ __forceinline__ float tanhf_(float v) {
    return 1.0f - 2.0f / (__expf(2.0f * v) + 1.0f);
}

__device__ __forceinline__ void gll16(const void* g, void* l) {
    __builtin_amdgcn_global_load_lds(
        (const __attribute__((address_space(1))) void*)g,
        (__attribute__((address_space(3))) void*)l,
        16, 0, 0);
}

// Core: C[128x128] tile of A(M x lda) * B(N x ldb)^T, both bf16 K-contiguous.
// 4 waves, each 64x64 via 4x4 grid of 16x16x32 MFMAs.
// LDS is XOR-swizzled (conflict-free, verified R2: SQ_LDS_BANK_CONFLICT=0):
// physical 16B-block p in row r holds global column-block p ^ (r&7).
__device__ __forceinline__ void mma_core(
    const unsigned short* __restrict__ A, int lda,
    const unsigned short* __restrict__ B, int ldb,
    int m0, int n0, int nk, int remap_from, int remap_add,
    unsigned short* As, unsigned short* Bs, f32x4 acc[4][4])
{
    const int t = threadIdx.x;
    const int lane = t & 63;
    const int wm = (t >> 7) & 1;
    const int wn = (t >> 6) & 1;
    const int srow = t >> 3;                         // staging row (0..31)
    const int ldsCol = (t & 7) * 8;                  // physical LDS col (elems)
    const int swc = (((t & 7) ^ ((t >> 3) & 7))) * 8;  // swizzled global col

    for (int kt = 0; kt < nk; ++kt) {
        int k0 = kt * BK + (kt >= remap_from ? remap_add : 0);
        __syncthreads();
        #pragma unroll
        for (int j = 0; j < 4; ++j) {
            int row = j * 32 + srow;
            gll16(A + (size_t)(m0 + row) * lda + k0 + swc, As + row * BK + ldsCol);
            gll16(B + (size_t)(n0 + row) * ldb + k0 + swc, Bs + row * BK + ldsCol);
        }
        __syncthreads();
        #pragma unroll
        for (int kk = 0; kk < 2; ++kk) {
            bf16x8 af[4], bfr[4];
            // fragment row r satisfies r&7 == lane&7, so swizzle is (lane&7)
            const int off = (((kk * 4 + (lane >> 4)) ^ (lane & 7))) * 8;
            const int ra = (wm * 64 + (lane & 15)) * BK + off;
            const int rb = (wn * 64 + (lane & 15)) * BK + off;
            #pragma unroll
            for (int i = 0; i < 4; ++i)
                af[i] = *(const bf16x8*)(As + ra + i * 16 * BK);
            #pragma unroll
            for (int j = 0; j < 4; ++j)
                bfr[j] = *(const bf16x8*)(Bs + rb + j * 16 * BK);
            #pragma unroll
            for (int i = 0; i < 4; ++i)
                #pragma unroll
                for (int j = 0; j < 4; ++j)
                    acc[i][j] = __builtin_amdgcn_mfma_f32_16x16x32_bf16(
                        af[i], bfr[j], acc[i][j], 0, 0, 0);
        }
    }
}

// GEMM1: S = Xall(8192x4096) @ Wcat(3072x4096)^T, fused gate epilogues.
// grid = 1536 linear blocks; XCD-swizzled; gate-balanced bn interleave.
// __launch_bounds__(256,3): cap unified VGPR+AGPR at 168 -> 3 blocks/CU.
__global__ __launch_bounds__(256, 3) void gemm1(
    const unsigned short* __restrict__ Xall,
    const unsigned short* __restrict__ Wcat,
    const float* __restrict__ hprev,
    const float* __restrict__ br, const float* __restrict__ bz,
    unsigned short* __restrict__ rh,   // bf16 8192x1024
    float* __restrict__ zout,          // fp32 8192x1024 (aliases d_out)
    float* __restrict__ shp)           // fp32 8192x1024
{
    __shared__ __attribute__((aligned(16))) unsigned short As[BM * BK];
    __shared__ __attribute__((aligned(16))) unsigned short Bs[BN * BK];
    f32x4 acc[4][4] = {};

    // XCD swizzle: consecutive flat ids round-robin XCDs; each XCD gets a
    // contiguous 16bm stripe x 12 interleaved bn columns (4 per gate, so
    // nk=48 gate-h work is balanced across XCDs).
    const int flat = blockIdx.y * gridDim.x + blockIdx.x;
    const int xcd = flat & 7;
    const int p = flat >> 3;                 // 0..191
    const int bm = (xcd >> 1) * 16 + (p & 15);
    const int bn = (p >> 4) * 2 + (xcd & 1); // 12 columns, stride 2

    const int gate = (bn * BN) >> 10;        // 0=r, 1=z, 2=h
    const int m0 = bm * BM, n0 = bn * BN;
    const int nk = (gate == 2) ? 48 : 64;    // gate h skips dead Uh segment
    const int rfrom = (gate == 2) ? 16 : (1 << 30);

    mma_core(Xall, 4096, Wcat, 4096, m0, n0, nk, rfrom, 1024, As, Bs, acc);

    const int lane = threadIdx.x & 63;
    const int wm = (threadIdx.x >> 7) & 1, wn = (threadIdx.x >> 6) & 1;
    const int rowb = m0 + wm * 64 + (lane >> 4) * 4;
    const int colb = (n0 - gate * 1024) + wn * 64 + (lane & 15);

    if (gate == 0) {
        #pragma unroll
        for (int i = 0; i < 4; ++i)
            #pragma unroll
            for (int r = 0; r < 4; ++r) {
                int m = rowb + i * 16 + r;
                #pragma unroll
                for (int j = 0; j < 4; ++j) {
                    int n = colb + j * 16;
                    size_t idx = (size_t)m * 1024 + n;
                    float rr = sigmoidf_(acc[i][j][r] + br[n]);
                    rh[idx] = f2b(rr * hprev[idx]);
                }
            }
    } else if (gate == 1) {
        #pragma unroll
        for (int i = 0; i < 4; ++i)
            #pragma unroll
            for (int r = 0; r < 4; ++r) {
                int m = rowb + i * 16 + r;
                #pragma unroll
                for (int j = 0; j < 4; ++j) {
                    int n = colb + j * 16;
                    size_t idx = (size_t)m * 1024 + n;
                    zout[idx] = sigmoidf_(acc[i][j][r] + bz[n]);
                }
            }
    } else {
        #pragma unroll
        for (int i = 0; i < 4; ++i)
            #pragma unroll
            for (int r = 0; r < 4; ++r) {
                int m = rowb + i * 16 + r;
                #pragma unroll
                for (int j = 0; j < 4; ++j) {
                    int n = colb + j * 16;
                    size_t idx = (size_t)m * 1024 + n;
                    shp[idx] = acc[i][j][r];
                }
            }
    }
}

// GEMM2: Sh2 = rh(8192x1024) @ Uhb(1024x1024)^T; epilogue computes final out.
// grid = 512 linear blocks; 8bm x 8bn region per XCD.
__global__ __launch_bounds__(256, 3) void gemm2(
    const unsigned short* __restrict__ rh,
    const unsigned short* __restrict__ Uhb,
    const float* __restrict__ shp, const float* __restrict__ bh,
    const float* __restrict__ hprev,
    float* __restrict__ zo)            // in: z, out: final (d_out)
{
    __shared__ __attribute__((aligned(16))) unsigned short As[BM * BK];
    __shared__ __attribute__((aligned(16))) unsigned short Bs[BN * BK];
    f32x4 acc[4][4] = {};

    const int flat = blockIdx.y * gridDim.x + blockIdx.x;
    const int xcd = flat & 7;
    const int p = flat >> 3;                 // 0..63
    const int bm = xcd * 8 + (p & 7);
    const int bn = p >> 3;
    const int m0 = bm * BM, n0 = bn * BN;

    mma_core(rh, 1024, Uhb, 1024, m0, n0, 16, 1 << 30, 0, As, Bs, acc);

    const int lane = threadIdx.x & 63;
    const int wm = (threadIdx.x >> 7) & 1, wn = (threadIdx.x >> 6) & 1;
    const int rowb = m0 + wm * 64 + (lane >> 4) * 4;
    const int colb = n0 + wn * 64 + (lane & 15);

    #pragma unroll
    for (int i = 0; i < 4; ++i)
        #pragma unroll
        for (int r = 0; r < 4; ++r) {
            int m = rowb + i * 16 + r;
            #pragma unroll
            for (int j = 0; j < 4; ++j) {
                int n = colb + j * 16;
                size_t idx = (size_t)m * 1024 + n;
                float val = acc[i][j][r] + shp[idx] + bh[n];
                float hp = tanhf_(val);
                float zv = zo[idx];
                zo[idx] = zv * hp + (1.0f - zv) * hprev[idx];
            }
        }
}

// fp32 -> bf16 strided copy-cast, 12 jobs in one launch. 8 floats/thread,
// 16B stores. grid = (2048, 12).
struct CastJobs {
    const float* src[12];
    unsigned short* dst[12];   // pre-offset by dst col0
    int n8[12];                // groups of 8 floats
    int cs3[12];               // log2(src cols) - 3
    int stride[12];            // dst row stride in elements
};

__global__ __launch_bounds__(256) void cast_all(CastJobs jb) {
    const int job = blockIdx.y;
    const float4* src = (const float4*)jb.src[job];
    unsigned short* dst = jb.dst[job];
    const int n8 = jb.n8[job];
    const int cs3 = jb.cs3[job];
    const int stride = jb.stride[job];
    const int cmask = (1 << cs3) - 1;
    for (int i = blockIdx.x * blockDim.x + threadIdx.x; i < n8;
         i += gridDim.x * blockDim.x) {
        float4 a = src[2 * i];
        float4 b = src[2 * i + 1];
        int row = i >> cs3;
        int col = (i & cmask) * 8;
        u16x8 o;
        o[0] = f2b(a.x); o[1] = f2b(a.y); o[2] = f2b(a.z); o[3] = f2b(a.w);
        o[4] = f2b(b.x); o[5] = f2b(b.y); o[6] = f2b(b.z); o[7] = f2b(b.w);
        *(u16x8*)(dst + (size_t)row * stride + col) = o;
    }
}

extern "C" void kernel_launch(void* const* d_in, const int* in_sizes, int n_in,
                              void* d_out, int out_size, void* d_ws, size_t ws_size,
                              hipStream_t stream) {
    const float* x     = (const float*)d_in[0];
    const float* hprev = (const float*)d_in[1];
    const float* c     = (const float*)d_in[2];
    const float* Wh    = (const float*)d_in[3];
    const float* Wz    = (const float*)d_in[4];
    const float* Wr    = (const float*)d_in[5];
    const float* Uh    = (const float*)d_in[6];
    const float* Uz    = (const float*)d_in[7];
    const float* Ur    = (const float*)d_in[8];
    const float* Ch    = (const float*)d_in[9];
    const float* Cz    = (const float*)d_in[10];
    const float* Cr    = (const float*)d_in[11];
    const float* bh    = (const float*)d_in[12];
    const float* bz    = (const float*)d_in[13];
    const float* br    = (const float*)d_in[14];

    char* ws = (char*)d_ws;
    unsigned short* Xall = (unsigned short*)ws; ws += (size_t)8192 * 4096 * 2;
    unsigned short* Wcat = (unsigned short*)ws; ws += (size_t)3072 * 4096 * 2;
    unsigned short* Uhb  = (unsigned short*)ws; ws += (size_t)1024 * 1024 * 2;
    unsigned short* rhb  = (unsigned short*)ws; ws += (size_t)8192 * 1024 * 2;
    float* shp           = (float*)ws;          ws += (size_t)8192 * 1024 * 4;
    float* zo = (float*)d_out;   // z staged in d_out, overwritten with final out

    CastJobs jb;
    auto setjob = [&](int j, const float* s, unsigned short* dbase, int col0,
                      int rows, int cols, int stride) {
        jb.src[j] = s; jb.dst[j] = dbase + col0;
        jb.n8[j] = rows * cols / 8;
        jb.cs3[j] = (cols == 2048) ? 8 : 7;
        jb.stride[j] = stride;
    };
    // Xall = [x | hprev | c]
    setjob(0, x,     Xall, 0,    8192, 1024, 4096);
    setjob(1, hprev, Xall, 1024, 8192, 1024, 4096);
    setjob(2, c,     Xall, 2048, 8192, 2048, 4096);
    // Wcat rows 0..1023 = [Wr|Ur|Cr]
    setjob(3, Wr, Wcat, 0,    1024, 1024, 4096);
    setjob(4, Ur, Wcat, 1024, 1024, 1024, 4096);
    setjob(5, Cr, Wcat, 2048, 1024, 2048, 4096);
    // rows 1024..2047 = [Wz|Uz|Cz]
    setjob(6, Wz, Wcat + 1024 * 4096, 0,    1024, 1024, 4096);
    setjob(7, Uz, Wcat + 1024 * 4096, 1024, 1024, 1024, 4096);
    setjob(8, Cz, Wcat + 1024 * 4096, 2048, 1024, 2048, 4096);
    // rows 2048..3071 = [Wh|unused|Ch] (dead segment never read: gate-h K-loop skips it)
    setjob(9,  Wh, Wcat + 2048 * 4096, 0,    1024, 1024, 4096);
    setjob(10, Ch, Wcat + 2048 * 4096, 2048, 1024, 2048, 4096);
    // Uh standalone
    setjob(11, Uh, Uhb, 0, 1024, 1024, 1024);

    hipLaunchKernelGGL(cast_all, dim3(2048, 12), dim3(256), 0, stream, jb);
    hipLaunchKernelGGL(gemm1, dim3(24, 64), dim3(256), 0, stream,
                       Xall, Wcat, hprev, br, bz, rhb, zo, shp);
    hipLaunchKernelGGL(gemm2, dim3(8, 64), dim3(256), 0, stream,
                       rhb, Uhb, shp, bh, hprev, zo);
}

// Round 4
// 435.385 us; speedup vs baseline: 1.2478x; 1.0080x over previous
//
#include <hip/hip_runtime.h>
#include <hip/hip_bf16.h>

typedef __attribute__((ext_vector_type(8))) short bf16x8;
typedef __attribute__((ext_vector_type(8))) unsigned short u16x8;
typedef __attribute__((ext_vector_type(4))) float f32x4;

#define BM 128
#define BN 128
#define BK 64

__device__ __forceinline__ unsigned short f2b(float f) {
    union { float f; unsigned int u; } x; x.f = f;
    unsigned int r = x.u + 0x7fffu + ((x.u >> 16) & 1u);
    return (unsigned short)(r >> 16);
}
__device__ __forceinline__ float b2f(unsigned short b) {
    union { unsigned int u; float f; } x; x.u = ((unsigned int)b) << 16;
    return x.f;
}

__device__ __forceinline__ float sigmoidf_(float v) {
    return 1.0f / (1.0f + __expf(-v));
}
__device__ __forceinline__ float tanhf_(float v) {
    return 1.0f - 2.0f / (__expf(2.0f * v) + 1.0f);
}

__device__ __forceinline__ void gll16(const void* g, void* l) {
    __builtin_amdgcn_global_load_lds(
        (const __attribute__((address_space(1))) void*)g,
        (__attribute__((address_space(3))) void*)l,
        16, 0, 0);
}

// Core: C[128x128] tile of A(M x lda) * B(N x ldb)^T, both bf16 K-contiguous.
// 4 waves, each 64x64 via 4x4 grid of 16x16x32 MFMAs.
// LDS is XOR-swizzled (conflict-free, verified R2: SQ_LDS_BANK_CONFLICT=0):
// physical 16B-block p in row r holds global column-block p ^ (r&7).
__device__ __forceinline__ void mma_core(
    const unsigned short* __restrict__ A, int lda,
    const unsigned short* __restrict__ B, int ldb,
    int m0, int n0, int nk, int remap_from, int remap_add,
    unsigned short* As, unsigned short* Bs, f32x4 acc[4][4])
{
    const int t = threadIdx.x;
    const int lane = t & 63;
    const int wm = (t >> 7) & 1;
    const int wn = (t >> 6) & 1;
    const int srow = t >> 3;                         // staging row (0..31)
    const int ldsCol = (t & 7) * 8;                  // physical LDS col (elems)
    const int swc = (((t & 7) ^ ((t >> 3) & 7))) * 8;  // swizzled global col

    for (int kt = 0; kt < nk; ++kt) {
        int k0 = kt * BK + (kt >= remap_from ? remap_add : 0);
        __syncthreads();
        #pragma unroll
        for (int j = 0; j < 4; ++j) {
            int row = j * 32 + srow;
            gll16(A + (size_t)(m0 + row) * lda + k0 + swc, As + row * BK + ldsCol);
            gll16(B + (size_t)(n0 + row) * ldb + k0 + swc, Bs + row * BK + ldsCol);
        }
        __syncthreads();
        #pragma unroll
        for (int kk = 0; kk < 2; ++kk) {
            bf16x8 af[4], bfr[4];
            // fragment row r satisfies r&7 == lane&7, so swizzle is (lane&7)
            const int off = (((kk * 4 + (lane >> 4)) ^ (lane & 7))) * 8;
            const int ra = (wm * 64 + (lane & 15)) * BK + off;
            const int rb = (wn * 64 + (lane & 15)) * BK + off;
            #pragma unroll
            for (int i = 0; i < 4; ++i)
                af[i] = *(const bf16x8*)(As + ra + i * 16 * BK);
            #pragma unroll
            for (int j = 0; j < 4; ++j)
                bfr[j] = *(const bf16x8*)(Bs + rb + j * 16 * BK);
            #pragma unroll
            for (int i = 0; i < 4; ++i)
                #pragma unroll
                for (int j = 0; j < 4; ++j)
                    acc[i][j] = __builtin_amdgcn_mfma_f32_16x16x32_bf16(
                        af[i], bfr[j], acc[i][j], 0, 0, 0);
        }
    }
}

// GEMM1: S = Xall(8192x4096) @ Wcat(3072x4096)^T, fused gate epilogues.
// grid = 1536 linear blocks; XCD-swizzled; gate-balanced bn interleave.
// (256,4): regs fit exactly at 64 VGPR + 64 AGPR = 128 -> 4 blocks/CU.
__global__ __launch_bounds__(256, 4) void gemm1(
    const unsigned short* __restrict__ Xall,
    const unsigned short* __restrict__ Wcat,
    const float* __restrict__ hprev,
    const float* __restrict__ br, const float* __restrict__ bz,
    unsigned short* __restrict__ rh,   // bf16 8192x1024
    unsigned short* __restrict__ zs,   // bf16 8192x1024
    unsigned short* __restrict__ shp)  // bf16 8192x1024 (gate-h partial preact)
{
    __shared__ __attribute__((aligned(16))) unsigned short As[BM * BK];
    __shared__ __attribute__((aligned(16))) unsigned short Bs[BN * BK];
    f32x4 acc[4][4] = {};

    // XCD swizzle: consecutive flat ids round-robin XCDs; each XCD gets a
    // contiguous 16bm stripe x 12 interleaved bn columns (4 per gate).
    const int flat = blockIdx.y * gridDim.x + blockIdx.x;
    const int xcd = flat & 7;
    const int p = flat >> 3;                 // 0..191
    const int bm = (xcd >> 1) * 16 + (p & 15);
    const int bn = (p >> 4) * 2 + (xcd & 1); // 12 columns, stride 2

    const int gate = (bn * BN) >> 10;        // 0=r, 1=z, 2=h
    const int m0 = bm * BM, n0 = bn * BN;
    const int nk = (gate == 2) ? 48 : 64;    // gate h skips dead Uh segment
    const int rfrom = (gate == 2) ? 16 : (1 << 30);

    mma_core(Xall, 4096, Wcat, 4096, m0, n0, nk, rfrom, 1024, As, Bs, acc);

    const int lane = threadIdx.x & 63;
    const int wm = (threadIdx.x >> 7) & 1, wn = (threadIdx.x >> 6) & 1;
    const int rowb = m0 + wm * 64 + (lane >> 4) * 4;
    const int colb = (n0 - gate * 1024) + wn * 64 + (lane & 15);

    if (gate == 0) {
        #pragma unroll
        for (int i = 0; i < 4; ++i)
            #pragma unroll
            for (int r = 0; r < 4; ++r) {
                int m = rowb + i * 16 + r;
                #pragma unroll
                for (int j = 0; j < 4; ++j) {
                    int n = colb + j * 16;
                    size_t idx = (size_t)m * 1024 + n;
                    float rr = sigmoidf_(acc[i][j][r] + br[n]);
                    rh[idx] = f2b(rr * hprev[idx]);
                }
            }
    } else if (gate == 1) {
        #pragma unroll
        for (int i = 0; i < 4; ++i)
            #pragma unroll
            for (int r = 0; r < 4; ++r) {
                int m = rowb + i * 16 + r;
                #pragma unroll
                for (int j = 0; j < 4; ++j) {
                    int n = colb + j * 16;
                    size_t idx = (size_t)m * 1024 + n;
                    zs[idx] = f2b(sigmoidf_(acc[i][j][r] + bz[n]));
                }
            }
    } else {
        #pragma unroll
        for (int i = 0; i < 4; ++i)
            #pragma unroll
            for (int r = 0; r < 4; ++r) {
                int m = rowb + i * 16 + r;
                #pragma unroll
                for (int j = 0; j < 4; ++j) {
                    int n = colb + j * 16;
                    size_t idx = (size_t)m * 1024 + n;
                    shp[idx] = f2b(acc[i][j][r]);
                }
            }
    }
}

// GEMM2: Sh2 = rh(8192x1024) @ Uhb(1024x1024)^T; epilogue computes final out.
// grid = 512 linear blocks; 8bm x 8bn region per XCD.
__global__ __launch_bounds__(256, 4) void gemm2(
    const unsigned short* __restrict__ rh,
    const unsigned short* __restrict__ Uhb,
    const unsigned short* __restrict__ shp, const float* __restrict__ bh,
    const unsigned short* __restrict__ zs,
    const float* __restrict__ hprev,
    float* __restrict__ out)           // d_out
{
    __shared__ __attribute__((aligned(16))) unsigned short As[BM * BK];
    __shared__ __attribute__((aligned(16))) unsigned short Bs[BN * BK];
    f32x4 acc[4][4] = {};

    const int flat = blockIdx.y * gridDim.x + blockIdx.x;
    const int xcd = flat & 7;
    const int p = flat >> 3;                 // 0..63
    const int bm = xcd * 8 + (p & 7);
    const int bn = p >> 3;
    const int m0 = bm * BM, n0 = bn * BN;

    mma_core(rh, 1024, Uhb, 1024, m0, n0, 16, 1 << 30, 0, As, Bs, acc);

    const int lane = threadIdx.x & 63;
    const int wm = (threadIdx.x >> 7) & 1, wn = (threadIdx.x >> 6) & 1;
    const int rowb = m0 + wm * 64 + (lane >> 4) * 4;
    const int colb = n0 + wn * 64 + (lane & 15);

    #pragma unroll
    for (int i = 0; i < 4; ++i)
        #pragma unroll
        for (int r = 0; r < 4; ++r) {
            int m = rowb + i * 16 + r;
            #pragma unroll
            for (int j = 0; j < 4; ++j) {
                int n = colb + j * 16;
                size_t idx = (size_t)m * 1024 + n;
                float val = acc[i][j][r] + b2f(shp[idx]) + bh[n];
                float hp = tanhf_(val);
                float zv = b2f(zs[idx]);
                out[idx] = zv * hp + (1.0f - zv) * hprev[idx];
            }
        }
}

// fp32 -> bf16 strided copy-cast, 12 jobs, flat-indexed (load-balanced).
// Each flat index i handles 8 consecutive floats of its job.
struct CastJobs {
    const float* src[12];
    unsigned short* dst[12];   // pre-offset by dst col0
    int start[13];             // prefix sums in n8 units
    int cs3[12];               // log2(src cols) - 3
    int stride[12];            // dst row stride in elements
};

__global__ __launch_bounds__(256) void cast_all(CastJobs jb, int total) {
    for (int i = blockIdx.x * blockDim.x + threadIdx.x; i < total;
         i += gridDim.x * blockDim.x) {
        int j = 0;
        #pragma unroll
        for (int k = 1; k < 12; ++k) j += (i >= jb.start[k]) ? 1 : 0;
        const int li = i - jb.start[j];
        const float4* src = (const float4*)jb.src[j];
        float4 a = src[2 * li];
        float4 b = src[2 * li + 1];
        const int cs3 = jb.cs3[j];
        int row = li >> cs3;
        int col = (li & ((1 << cs3) - 1)) * 8;
        u16x8 o;
        o[0] = f2b(a.x); o[1] = f2b(a.y); o[2] = f2b(a.z); o[3] = f2b(a.w);
        o[4] = f2b(b.x); o[5] = f2b(b.y); o[6] = f2b(b.z); o[7] = f2b(b.w);
        *(u16x8*)(jb.dst[j] + (size_t)row * jb.stride[j] + col) = o;
    }
}

extern "C" void kernel_launch(void* const* d_in, const int* in_sizes, int n_in,
                              void* d_out, int out_size, void* d_ws, size_t ws_size,
                              hipStream_t stream) {
    const float* x     = (const float*)d_in[0];
    const float* hprev = (const float*)d_in[1];
    const float* c     = (const float*)d_in[2];
    const float* Wh    = (const float*)d_in[3];
    const float* Wz    = (const float*)d_in[4];
    const float* Wr    = (const float*)d_in[5];
    const float* Uh    = (const float*)d_in[6];
    const float* Uz    = (const float*)d_in[7];
    const float* Ur    = (const float*)d_in[8];
    const float* Ch    = (const float*)d_in[9];
    const float* Cz    = (const float*)d_in[10];
    const float* Cr    = (const float*)d_in[11];
    const float* bh    = (const float*)d_in[12];
    const float* bz    = (const float*)d_in[13];
    const float* br    = (const float*)d_in[14];

    char* ws = (char*)d_ws;
    unsigned short* Xall = (unsigned short*)ws; ws += (size_t)8192 * 4096 * 2;
    unsigned short* Wcat = (unsigned short*)ws; ws += (size_t)3072 * 4096 * 2;
    unsigned short* Uhb  = (unsigned short*)ws; ws += (size_t)1024 * 1024 * 2;
    unsigned short* rhb  = (unsigned short*)ws; ws += (size_t)8192 * 1024 * 2;
    unsigned short* shp  = (unsigned short*)ws; ws += (size_t)8192 * 1024 * 2;
    unsigned short* zsb  = (unsigned short*)ws; ws += (size_t)8192 * 1024 * 2;

    CastJobs jb;
    int acc = 0;
    auto setjob = [&](int j, const float* s, unsigned short* dbase, int col0,
                      int rows, int cols, int stride) {
        jb.src[j] = s; jb.dst[j] = dbase + col0;
        jb.start[j] = acc;
        acc += rows * cols / 8;
        jb.cs3[j] = (cols == 2048) ? 8 : 7;
        jb.stride[j] = stride;
    };
    // Xall = [x | hprev | c]
    setjob(0, x,     Xall, 0,    8192, 1024, 4096);
    setjob(1, hprev, Xall, 1024, 8192, 1024, 4096);
    setjob(2, c,     Xall, 2048, 8192, 2048, 4096);
    // Wcat rows 0..1023 = [Wr|Ur|Cr]
    setjob(3, Wr, Wcat, 0,    1024, 1024, 4096);
    setjob(4, Ur, Wcat, 1024, 1024, 1024, 4096);
    setjob(5, Cr, Wcat, 2048, 1024, 2048, 4096);
    // rows 1024..2047 = [Wz|Uz|Cz]
    setjob(6, Wz, Wcat + 1024 * 4096, 0,    1024, 1024, 4096);
    setjob(7, Uz, Wcat + 1024 * 4096, 1024, 1024, 1024, 4096);
    setjob(8, Cz, Wcat + 1024 * 4096, 2048, 1024, 2048, 4096);
    // rows 2048..3071 = [Wh|unused|Ch] (dead segment never read)
    setjob(9,  Wh, Wcat + 2048 * 4096, 0,    1024, 1024, 4096);
    setjob(10, Ch, Wcat + 2048 * 4096, 2048, 1024, 2048, 4096);
    // Uh standalone
    setjob(11, Uh, Uhb, 0, 1024, 1024, 1024);
    jb.start[12] = acc;

    hipLaunchKernelGGL(cast_all, dim3(2048), dim3(256), 0, stream, jb, acc);
    hipLaunchKernelGGL(gemm1, dim3(24, 64), dim3(256), 0, stream,
                       Xall, Wcat, hprev, br, bz, rhb, zsb, shp);
    hipLaunchKernelGGL(gemm2, dim3(8, 64), dim3(256), 0, stream,
                       rhb, Uhb, shp, bh, zsb, hprev, (float*)d_out);
}